// Round 4
// baseline (18.007 us; speedup 1.0000x reference)
//
#include <hip/hip_runtime.h>
#include <hip/hip_bf16.h>

#define L_LEN 64
#define N_TOPICS 81
#define ROWS_PER_WAVE 8
#define ROWS_PER_BLOCK 32     // 4 waves/block * 8 rows/wave

// All-register structure, everything 16B/lane:
//  - 8 lanes per row. Each lane: 2x int4 label loads (coalesced).
//  - Membership = 96-bit topic bitmask in 3 VGPRs, OR-reduced over the 8-lane
//    group with 9 shfl_xor. No LDS.
//  - P read as ALIGNED float4 from the aligned-down window of the row
//    (row*81 dwords == row*81 & ~3 + off, off = row & 3 since 81 % 4 == 1).
//    Window dword d corresponds to topic d - off; test bit d of (mask << off).
//    Window = 84 dwords = 21 float4 -> t=0,1 for all lanes, t=2 for lig<=4.
//  - Masked max (P >= 0, init 0 == reference's max(0, .)), 3-stage fmax
//    butterfly, lane 0 of group writes -v.
__global__ __launch_bounds__(256) void rangeshrink_max_kernel(
    const float* __restrict__ P,
    const int* __restrict__ hard_label,
    const int* __restrict__ sent_idx,
    float* __restrict__ out,
    int nrows)
{
    const int wave = threadIdx.x >> 6;
    const int lane = threadIdx.x & 63;
    const int g    = lane >> 3;          // row within wave (0..7)
    const int lig  = lane & 7;           // lane in group (0..7)

    const int row = blockIdx.x * ROWS_PER_BLOCK + wave * ROWS_PER_WAVE + g;
    if (row >= nrows) return;

    // ---- P window loads (aligned float4), issued first ----
    const size_t base_dw = (size_t)row * N_TOPICS;
    const int    off     = row & 3;                      // base_dw & 3, since 81 % 4 == 1
    const size_t a0      = base_dw - off;                // 16B-aligned dword index
    const float4* __restrict__ W4 = (const float4*)(P + a0);

    const int f2 = lig + 16;
    // t2 needed only for f2 <= 20 (window is 21 float4). For the last row,
    // f2 == 20 is in-bounds iff off == 3; guard the general case.
    const bool ok2 = (f2 <= 20) && ((row < nrows - 1) || (4 * f2 + 3 <= 80 + off));

    float4 p0 = W4[lig];
    float4 p1 = W4[lig + 8];
    float4 p2 = ok2 ? W4[f2] : make_float4(0.f, 0.f, 0.f, 0.f);

    // ---- labels (2x int4, coalesced) + sent_idx ----
    const int4* __restrict__ hl4 = (const int4*)hard_label;
    const int4 la = hl4[(size_t)row * 16 + lig * 2];
    const int4 lb = hl4[(size_t)row * 16 + lig * 2 + 1];
    const int  si = sent_idx[row];

    // ---- build per-lane 96-bit topic mask ----
    unsigned m0 = 0u, m1 = 0u, m2 = 0u;
    const int labs[8] = { la.x, la.y, la.z, la.w, lb.x, lb.y, lb.z, lb.w };
    #pragma unroll
    for (int k = 0; k < 8; ++k) {
        const int j   = lig * 8 + k;                     // position in row
        const int lab = labs[k];
        const bool valid = (j >= si) && (lab >= 0);
        const unsigned b = 1u << (lab & 31);
        const int w = lab >> 5;                          // 0..2 (lab <= 80)
        m0 |= (valid && w == 0) ? b : 0u;
        m1 |= (valid && w == 1) ? b : 0u;
        m2 |= (valid && w == 2) ? b : 0u;
    }

    // ---- OR-reduce mask across the 8-lane group ----
    #pragma unroll
    for (int o = 1; o < 8; o <<= 1) {
        m0 |= __shfl_xor(m0, o, 64);
        m1 |= __shfl_xor(m1, o, 64);
        m2 |= __shfl_xor(m2, o, 64);
    }

    // ---- shift mask by off: window bit d <-> topic d - off ----
    const unsigned long long lo = (unsigned long long)m0 | ((unsigned long long)m1 << 32);
    const unsigned long long hi = (unsigned long long)m1 | ((unsigned long long)m2 << 32);
    const unsigned long long slo = lo << off;
    const unsigned s0 = (unsigned)slo;
    const unsigned s1 = (unsigned)(slo >> 32);
    const unsigned s2 = (unsigned)((hi << off) >> 32);

    // ---- masked max: word index == t, bit == 4*lig + e ----
    const unsigned n0 = (s0 >> (4 * lig)) & 0xFu;
    const unsigned n1 = (s1 >> (4 * lig)) & 0xFu;
    const unsigned n2 = (s2 >> (4 * lig)) & 0xFu;

    float v = 0.0f;
    const float e0[4] = { p0.x, p0.y, p0.z, p0.w };
    const float e1[4] = { p1.x, p1.y, p1.z, p1.w };
    const float e2[4] = { p2.x, p2.y, p2.z, p2.w };
    #pragma unroll
    for (int e = 0; e < 4; ++e) {
        v = fmaxf(v, ((n0 >> e) & 1u) ? e0[e] : 0.0f);
        v = fmaxf(v, ((n1 >> e) & 1u) ? e1[e] : 0.0f);
        v = fmaxf(v, ((n2 >> e) & 1u) ? e2[e] : 0.0f);
    }

    // ---- 8-lane fmax butterfly ----
    #pragma unroll
    for (int o = 1; o < 8; o <<= 1) {
        v = fmaxf(v, __shfl_xor(v, o, 64));
    }

    if (lig == 0) out[row] = -v;
}

extern "C" void kernel_launch(void* const* d_in, const int* in_sizes, int n_in,
                              void* d_out, int out_size, void* d_ws, size_t ws_size,
                              hipStream_t stream) {
    const float* P          = (const float*)d_in[0];
    const int*   hard_label = (const int*)d_in[1];
    const int*   sent_idx   = (const int*)d_in[2];
    float*       out        = (float*)d_out;

    const int nrows = out_size;                                   // 131072
    const int grid = (nrows + ROWS_PER_BLOCK - 1) / ROWS_PER_BLOCK; // 4096

    rangeshrink_max_kernel<<<grid, 256, 0, stream>>>(P, hard_label, sent_idx, out, nrows);
}

// Round 5
// 17.258 us; speedup vs baseline: 1.0434x; 1.0434x over previous
//
#include <hip/hip_runtime.h>
#include <hip/hip_bf16.h>

#define N_TOPICS 81
#define ROWS_PER_WAVE 8
#define ROWS_PER_BLOCK 32      // 4 waves * 8 rows
#define ROW_STRIDE 88          // dwords per row LDS region
#define ZERO_SLOT 84           // stays 0.0f; gather target for invalid labels
#define TRASH_SLOT 86          // dump for out-of-range staged elements

// Balanced-pipe design: coalesced float4 P loads -> stage row into LDS at
// topic index -> per-label LDS gather + fmax. 8 lanes/row, 4 waves/block.
//  - P read via the aligned-down window: a0 = (row*81) & ~3, off = row & 3.
//    Window dword d holds topic d - off. 3 float4 loads/lane (t2: lig<=4).
//  - Stage: 12 b32 LDS writes/lane; topic t = 4*lig - off + e + 32*tt;
//    (unsigned)t <= 80 ? t : TRASH (single unsigned cmp covers both edges).
//  - Gather: valid = ((lig*8+k - si) | lab) >= 0 (sign-OR trick, 1 or + 1 cmp);
//    idx = valid ? lab : ZERO_SLOT (zeroed) -> ds_read_b32 -> fmax. No select.
//  - 3-stage 8-lane fmax butterfly; lig==0 writes -v (8 consecutive rows/wave).
// All LDS wave-private; wave_barrier pins zero/stage before gathers (per-wave
// DS ordering validated in R3).
__global__ __launch_bounds__(256) void rangeshrink_max_kernel(
    const float* __restrict__ P,
    const int* __restrict__ hard_label,
    const int* __restrict__ sent_idx,
    float* __restrict__ out,
    int nrows)
{
    __shared__ float lds[ROWS_PER_BLOCK * ROW_STRIDE];   // 32*88*4 = 11264 B

    const int wave = threadIdx.x >> 6;
    const int lane = threadIdx.x & 63;
    const int g    = lane >> 3;          // row within wave (0..7)
    const int lig  = lane & 7;           // lane in group (0..7)

    const int localRow = wave * ROWS_PER_WAVE + g;
    const int row = blockIdx.x * ROWS_PER_BLOCK + localRow;
    if (row >= nrows) return;            // grid divides exactly (131072/32)

    // ---- P window loads (aligned float4), issued first ----
    const size_t base_dw = (size_t)row * N_TOPICS;
    const int    off     = (int)(base_dw & 3);           // == row & 3
    const float4* __restrict__ W4 = (const float4*)(P + (base_dw - off));

    float4 p0 = W4[lig];                                 // window dwords 4lig..+3
    float4 p1 = W4[lig + 8];                             // +32
    float4 p2 = make_float4(0.f, 0.f, 0.f, 0.f);         // +64 (lig<=4 only)
    const bool ok2 = (lig <= 4) && ((row < nrows - 1) || (off == 3));
    if (ok2) p2 = W4[lig + 16];

    // ---- labels (2x int4, coalesced) + sent_idx (broadcast) ----
    const int4* __restrict__ hl4 = (const int4*)hard_label;
    const int4 la = hl4[(size_t)row * 16 + lig * 2];
    const int4 lb = hl4[(size_t)row * 16 + lig * 2 + 1];
    const int  si = sent_idx[row];

    // ---- stage P into LDS at topic index ----
    float* const srow = lds + localRow * ROW_STRIDE;
    if (lig == 0) srow[ZERO_SLOT] = 0.0f;                // gather-miss slot

    const int d0 = lig * 4 - off;                        // topic of p0.x
    const float pe0[4] = { p0.x, p0.y, p0.z, p0.w };
    const float pe1[4] = { p1.x, p1.y, p1.z, p1.w };
    const float pe2[4] = { p2.x, p2.y, p2.z, p2.w };
    #pragma unroll
    for (int e = 0; e < 4; ++e) {
        const int t0 = d0 + e;                           // -3..31
        srow[((unsigned)t0 <= 80u) ? t0 : TRASH_SLOT] = pe0[e];
        const int t1 = d0 + 32 + e;                      // 29..63, always valid
        srow[t1] = pe1[e];
        const int t2 = d0 + 64 + e;                      // 61..95
        srow[((unsigned)t2 <= 80u) ? t2 : TRASH_SLOT] = pe2[e];
    }
    __builtin_amdgcn_wave_barrier();                     // stage before gather

    // ---- per-label LDS gather + max ----
    const int base = lig * 8 - si;                       // position - sent_idx
    const int labs[8] = { la.x, la.y, la.z, la.w, lb.x, lb.y, lb.z, lb.w };
    float v = 0.0f;
    #pragma unroll
    for (int k = 0; k < 8; ++k) {
        // sign(m) set iff (base+k < 0) || (lab < 0)  -> invalid
        const int m   = (base + k) | labs[k];
        const int idx = (m < 0) ? ZERO_SLOT : labs[k];
        v = fmaxf(v, srow[idx]);
    }

    // ---- 8-lane fmax butterfly ----
    #pragma unroll
    for (int o = 1; o < 8; o <<= 1) {
        v = fmaxf(v, __shfl_xor(v, o, 64));
    }

    if (lig == 0) out[row] = -v;
}

extern "C" void kernel_launch(void* const* d_in, const int* in_sizes, int n_in,
                              void* d_out, int out_size, void* d_ws, size_t ws_size,
                              hipStream_t stream) {
    const float* P          = (const float*)d_in[0];
    const int*   hard_label = (const int*)d_in[1];
    const int*   sent_idx   = (const int*)d_in[2];
    float*       out        = (float*)d_out;

    const int nrows = out_size;                                     // 131072
    const int grid = (nrows + ROWS_PER_BLOCK - 1) / ROWS_PER_BLOCK; // 4096

    rangeshrink_max_kernel<<<grid, 256, 0, stream>>>(P, hard_label, sent_idx, out, nrows);
}

// Round 6
// 17.251 us; speedup vs baseline: 1.0438x; 1.0004x over previous
//
#include <hip/hip_runtime.h>
#include <hip/hip_bf16.h>

#define N_TOPICS 81
#define ROWS_PER_WAVE 8
#define ROWS_PER_BLOCK 32      // 4 waves * 8 rows
#define ROW_STRIDE 88          // dwords per row LDS region
#define ZERO_SLOT 84           // stays 0.0f; gather target for invalid labels
#define TRASH_SLOT 86          // dump for out-of-range staged elements

// R5 structure + dead-label-line skipping.
//  - 8 lanes/row. P read via aligned-down float4 window (3 loads/lane).
//  - Labels: 2x int4/lane, but an int4 whose 4 positions are ALL below
//    sent_idx is dead (masked by the reference) -> skip the load entirely
//    (exec-masked lanes fetch nothing; saves the row's first 64B line when
//    si >= 16, ~4 MB of HBM traffic) and substitute -1.
//  - Stage P into LDS at topic index (12 cond writes/lane), gather per label
//    with sign-OR validity -> ZERO_SLOT, fmax-reduce 8 lanes, write -v.
// All LDS wave-private; wave_barrier pins stage before gather (R3-validated).
__global__ __launch_bounds__(256) void rangeshrink_max_kernel(
    const float* __restrict__ P,
    const int* __restrict__ hard_label,
    const int* __restrict__ sent_idx,
    float* __restrict__ out,
    int nrows)
{
    __shared__ float lds[ROWS_PER_BLOCK * ROW_STRIDE];   // 11264 B

    const int wave = threadIdx.x >> 6;
    const int lane = threadIdx.x & 63;
    const int g    = lane >> 3;          // row within wave (0..7)
    const int lig  = lane & 7;           // lane in group (0..7)

    const int localRow = wave * ROWS_PER_WAVE + g;
    const int row = blockIdx.x * ROWS_PER_BLOCK + localRow;
    if (row >= nrows) return;            // 131072 % 32 == 0

    // ---- P window loads (aligned float4), issued first ----
    const size_t base_dw = (size_t)row * N_TOPICS;
    const int    off     = (int)(base_dw & 3);           // == row & 3
    const float4* __restrict__ W4 = (const float4*)(P + (base_dw - off));

    float4 p0 = W4[lig];                                 // window dwords 4lig..+3
    float4 p1 = W4[lig + 8];                             // +32
    float4 p2 = make_float4(0.f, 0.f, 0.f, 0.f);
    const bool ok2 = (lig <= 4) && ((row < nrows - 1) || (off == 3));
    if (ok2) p2 = W4[lig + 16];

    // ---- sent_idx, then conditionally-dead label loads ----
    const int si = sent_idx[row];

    const int4* __restrict__ hl4 = (const int4*)hard_label;
    int4 la = make_int4(-1, -1, -1, -1);
    int4 lb = make_int4(-1, -1, -1, -1);
    // la covers positions [8lig, 8lig+4): dead iff 8lig+4 <= si
    if (8 * lig + 4 > si) la = hl4[(size_t)row * 16 + lig * 2];
    // lb covers positions [8lig+4, 8lig+8): dead iff 8lig+8 <= si
    if (8 * lig + 8 > si) lb = hl4[(size_t)row * 16 + lig * 2 + 1];

    // ---- stage P into LDS at topic index ----
    float* const srow = lds + localRow * ROW_STRIDE;
    if (lig == 0) srow[ZERO_SLOT] = 0.0f;                // gather-miss slot

    const int d0 = lig * 4 - off;                        // topic of p0.x
    const float pe0[4] = { p0.x, p0.y, p0.z, p0.w };
    const float pe1[4] = { p1.x, p1.y, p1.z, p1.w };
    const float pe2[4] = { p2.x, p2.y, p2.z, p2.w };
    #pragma unroll
    for (int e = 0; e < 4; ++e) {
        const int t0 = d0 + e;                           // -3..31
        srow[((unsigned)t0 <= 80u) ? t0 : TRASH_SLOT] = pe0[e];
        const int t1 = d0 + 32 + e;                      // 29..63, always valid
        srow[t1] = pe1[e];
        const int t2 = d0 + 64 + e;                      // 61..95
        srow[((unsigned)t2 <= 80u) ? t2 : TRASH_SLOT] = pe2[e];
    }
    __builtin_amdgcn_wave_barrier();                     // stage before gather

    // ---- per-label LDS gather + max ----
    const int base = lig * 8 - si;                       // position - sent_idx
    const int labs[8] = { la.x, la.y, la.z, la.w, lb.x, lb.y, lb.z, lb.w };
    float v = 0.0f;
    #pragma unroll
    for (int k = 0; k < 8; ++k) {
        // sign(m) set iff (base+k < 0) || (lab < 0)  -> invalid
        const int m   = (base + k) | labs[k];
        const int idx = (m < 0) ? ZERO_SLOT : labs[k];
        v = fmaxf(v, srow[idx]);
    }

    // ---- 8-lane fmax butterfly ----
    #pragma unroll
    for (int o = 1; o < 8; o <<= 1) {
        v = fmaxf(v, __shfl_xor(v, o, 64));
    }

    if (lig == 0) out[row] = -v;
}

extern "C" void kernel_launch(void* const* d_in, const int* in_sizes, int n_in,
                              void* d_out, int out_size, void* d_ws, size_t ws_size,
                              hipStream_t stream) {
    const float* P          = (const float*)d_in[0];
    const int*   hard_label = (const int*)d_in[1];
    const int*   sent_idx   = (const int*)d_in[2];
    float*       out        = (float*)d_out;

    const int nrows = out_size;                                     // 131072
    const int grid = (nrows + ROWS_PER_BLOCK - 1) / ROWS_PER_BLOCK; // 4096

    rangeshrink_max_kernel<<<grid, 256, 0, stream>>>(P, hard_label, sent_idx, out, nrows);
}